// Round 1
// baseline (168.156 us; speedup 1.0000x reference)
//
#include <hip/hip_runtime.h>
#include <hip/hip_bf16.h>
#include <stdint.h>
#include <math.h>

#define N_NODES 8192
#define NDIM    512
#define HID     256
#define NCLS    16
#define NE      262144
#define MWR     256   // mask words per row (8192/32)
#define CAP     1024  // max neighbors stored per row (avg ~33, Poisson)

// ---------------------------------------------------------------------------
// Detect whether edge_index buffer is int64 or int32 (device-side, no host sync)
// If int64: all values in [0, 8192). If int32 read as int64: hi word is a
// second index (prob 1/8192 of being 0) -> essentially guaranteed out-of-range.
__global__ void detect_dtype(const void* edges, int* flag) {
    __shared__ int bad;
    if (threadIdx.x == 0) bad = 0;
    __syncthreads();
    const long long* p = (const long long*)edges;
    int lbad = 0;
    for (int i = threadIdx.x; i < 1024; i += 256) {
        long long v = p[i];
        if (v < 0 || v >= N_NODES) lbad = 1;
    }
    if (lbad) atomicOr(&bad, 1);
    __syncthreads();
    if (threadIdx.x == 0) *flag = bad;   // nonzero => int32 data
}

// ---------------------------------------------------------------------------
// Build dense adjacency bitmask (dedupes duplicate edges) + self loops.
__global__ void build_mask(const void* edges, const int* __restrict__ flag,
                           uint32_t* __restrict__ mask) {
    const int is32 = *flag;
    int idx = blockIdx.x * blockDim.x + threadIdx.x;
    if (idx < NE) {
        int src, dst;
        if (is32) {
            const int* p = (const int*)edges;
            src = p[idx]; dst = p[NE + idx];
        } else {
            const long long* p = (const long long*)edges;
            src = (int)p[idx]; dst = (int)p[NE + idx];
        }
        atomicOr(&mask[src * MWR + (dst >> 5)], 1u << (dst & 31));
    } else {
        int d = idx - NE;
        if (d < N_NODES) atomicOr(&mask[d * MWR + (d >> 5)], 1u << (d & 31));
    }
}

// ---------------------------------------------------------------------------
// h = x @ W^T   (M=8192, K=512, N=256), f32, 64x64 tiles, BK=32.
// xs/ws stored k-major with pad 68 (272B rows, 16B aligned) for conflict-free
// float4 LDS reads.
__global__ __launch_bounds__(256) void gemm_h(const float* __restrict__ x,
                                              const float* __restrict__ W,
                                              float* __restrict__ h) {
    __shared__ float xs[32][68];
    __shared__ float ws[32][68];
    const int tid  = threadIdx.x;
    const int row0 = blockIdx.y * 64;
    const int col0 = blockIdx.x * 64;
    const int lr = tid >> 3;          // 0..31
    const int lc = (tid & 7) << 2;    // 0,4,...,28
    const int tx = tid & 15;
    const int ty = tid >> 4;
    float acc[4][4] = {};
    const float* xp = x + (size_t)(row0 + lr) * NDIM + lc;
    const float* wp = W + (size_t)(col0 + lr) * NDIM + lc;

    for (int k0 = 0; k0 < NDIM; k0 += 32) {
        float4 xa = *(const float4*)(xp + k0);
        float4 xb = *(const float4*)(xp + k0 + 32 * NDIM);
        float4 wa = *(const float4*)(wp + k0);
        float4 wb = *(const float4*)(wp + k0 + 32 * NDIM);
        __syncthreads();
        xs[lc + 0][lr] = xa.x; xs[lc + 1][lr] = xa.y; xs[lc + 2][lr] = xa.z; xs[lc + 3][lr] = xa.w;
        xs[lc + 0][lr + 32] = xb.x; xs[lc + 1][lr + 32] = xb.y; xs[lc + 2][lr + 32] = xb.z; xs[lc + 3][lr + 32] = xb.w;
        ws[lc + 0][lr] = wa.x; ws[lc + 1][lr] = wa.y; ws[lc + 2][lr] = wa.z; ws[lc + 3][lr] = wa.w;
        ws[lc + 0][lr + 32] = wb.x; ws[lc + 1][lr + 32] = wb.y; ws[lc + 2][lr + 32] = wb.z; ws[lc + 3][lr + 32] = wb.w;
        __syncthreads();
        #pragma unroll
        for (int kk = 0; kk < 32; ++kk) {
            float4 a = *(const float4*)&xs[kk][ty << 2];
            float4 b = *(const float4*)&ws[kk][tx << 2];
            acc[0][0] += a.x * b.x; acc[0][1] += a.x * b.y; acc[0][2] += a.x * b.z; acc[0][3] += a.x * b.w;
            acc[1][0] += a.y * b.x; acc[1][1] += a.y * b.y; acc[1][2] += a.y * b.z; acc[1][3] += a.y * b.w;
            acc[2][0] += a.z * b.x; acc[2][1] += a.z * b.y; acc[2][2] += a.z * b.z; acc[2][3] += a.z * b.w;
            acc[3][0] += a.w * b.x; acc[3][1] += a.w * b.y; acc[3][2] += a.w * b.z; acc[3][3] += a.w * b.w;
        }
    }
    #pragma unroll
    for (int i = 0; i < 4; ++i) {
        float4 v = make_float4(acc[i][0], acc[i][1], acc[i][2], acc[i][3]);
        *(float4*)&h[(size_t)(row0 + (ty << 2) + i) * HID + col0 + (tx << 2)] = v;
    }
}

// ---------------------------------------------------------------------------
// f1 = h @ a1, f2 = h @ a2. One wave per row.
__global__ __launch_bounds__(256) void f1f2_kernel(const float* __restrict__ h,
                                                   const float* __restrict__ a1,
                                                   const float* __restrict__ a2,
                                                   float* __restrict__ f1,
                                                   float* __restrict__ f2) {
    int row  = blockIdx.x * 4 + (threadIdx.x >> 6);
    int lane = threadIdx.x & 63;
    float s1 = 0.f, s2 = 0.f;
    #pragma unroll
    for (int c = 0; c < HID; c += 64) {
        float hv = h[(size_t)row * HID + c + lane];
        s1 += hv * a1[c + lane];
        s2 += hv * a2[c + lane];
    }
    #pragma unroll
    for (int off = 32; off > 0; off >>= 1) {
        s1 += __shfl_down(s1, off);
        s2 += __shfl_down(s2, off);
    }
    if (lane == 0) { f1[row] = s1; f2[row] = s2; }
}

// ---------------------------------------------------------------------------
// Per-row: masked softmax over neighbors, out = elu(alpha @ h), logits = out@fc_w^T+fc_b
// One block (256 threads) per row. Thread t scans mask word t (32 cols).
__global__ __launch_bounds__(256) void aggregate(const uint32_t* __restrict__ mask,
                                                 const float* __restrict__ h,
                                                 const float* __restrict__ f1,
                                                 const float* __restrict__ f2,
                                                 const float* __restrict__ fc_w,
                                                 const float* __restrict__ fc_b,
                                                 float* __restrict__ out) {
    __shared__ int   sh_j[CAP];
    __shared__ float sh_v[CAP];
    __shared__ int   sh_cnt;
    __shared__ float red_m[256];
    __shared__ float red_s[256];
    __shared__ float sh_out[HID];

    const int row = blockIdx.x;
    const int tid = threadIdx.x;
    if (tid == 0) sh_cnt = 0;
    __syncthreads();

    const float fi = f1[row];
    uint32_t w = mask[(size_t)row * MWR + tid];
    // Online (max, sum) over this thread's valid entries; also append to list.
    float m = -INFINITY, s = 0.f;
    while (w) {
        int b = __ffs(w) - 1;
        w &= w - 1;
        int j = (tid << 5) + b;
        float z = fi + f2[j];
        float v = z > 0.f ? z : 0.01f * z;      // leaky_relu(0.01)
        if (v != 0.f) {                          // exact-zero entries are masked (ref quirk)
            int slot = atomicAdd(&sh_cnt, 1);
            if (slot < CAP) { sh_j[slot] = j; sh_v[slot] = v; }
            if (v > m) { s = s * expf(m - v) + 1.f; m = v; }
            else       { s += expf(v - m); }
        }
    }
    red_m[tid] = m;
    red_s[tid] = s;
    __syncthreads();
    // Block tree-reduce of (max, sum) pairs.
    for (int off = 128; off > 0; off >>= 1) {
        if (tid < off) {
            float ma = red_m[tid], sa = red_s[tid];
            float mb = red_m[tid + off], sb = red_s[tid + off];
            float M = fmaxf(ma, mb);
            float S = 0.f;
            if (ma != -INFINITY) S += sa * expf(ma - M);
            if (mb != -INFINITY) S += sb * expf(mb - M);
            red_m[tid] = M;
            red_s[tid] = S;
        }
        __syncthreads();
    }
    const float m_tot = red_m[0];
    const float s_tot = red_s[0];
    const int cnt = min(sh_cnt, CAP);
    __syncthreads();
    // Normalize weights in place.
    for (int n = tid; n < cnt; n += 256) {
        sh_v[n] = expf(sh_v[n] - m_tot) / s_tot;
    }
    __syncthreads();

    // alpha @ h : thread t owns hidden column t.
    float acc = 0.f;
    for (int n = 0; n < cnt; ++n) {
        acc += sh_v[n] * h[(size_t)sh_j[n] * HID + tid];
    }
    // ELU
    sh_out[tid] = acc > 0.f ? acc : expm1f(acc);
    __syncthreads();

    // FC: 16 classes x 16 segments
    const int c   = tid >> 4;
    const int seg = tid & 15;
    float p = 0.f;
    #pragma unroll
    for (int u = 0; u < 16; ++u) {
        int t = seg * 16 + u;
        p += sh_out[t] * fc_w[c * HID + t];
    }
    red_s[tid] = p;
    __syncthreads();
    if (tid < NCLS) {
        float t = fc_b[tid];
        #pragma unroll
        for (int q = 0; q < 16; ++q) t += red_s[tid * 16 + q];
        out[(size_t)row * NCLS + tid] = t;
    }
}

// ---------------------------------------------------------------------------
extern "C" void kernel_launch(void* const* d_in, const int* in_sizes, int n_in,
                              void* d_out, int out_size, void* d_ws, size_t ws_size,
                              hipStream_t stream) {
    const float* x    = (const float*)d_in[0];
    const void*  ei   = d_in[1];
    const float* W    = (const float*)d_in[2];
    const float* a1   = (const float*)d_in[3];
    const float* a2   = (const float*)d_in[4];
    const float* fc_w = (const float*)d_in[5];
    const float* fc_b = (const float*)d_in[6];
    float* out = (float*)d_out;

    char* ws = (char*)d_ws;
    uint32_t* mask = (uint32_t*)ws;                          // 8 MB
    float*    h    = (float*)(ws + (8u << 20));              // 8 MB
    float*    f1   = (float*)(ws + (16u << 20));             // 32 KB
    float*    f2   = (float*)(ws + (16u << 20) + (32u << 10));
    int*      flag = (int*)(ws + (16u << 20) + (64u << 10));

    hipMemsetAsync(mask, 0, (size_t)N_NODES * MWR * 4, stream);
    detect_dtype<<<1, 256, 0, stream>>>(ei, flag);
    int total = NE + N_NODES;
    build_mask<<<(total + 255) / 256, 256, 0, stream>>>(ei, flag, mask);
    gemm_h<<<dim3(HID / 64, N_NODES / 64), 256, 0, stream>>>(x, W, h);
    f1f2_kernel<<<N_NODES / 4, 256, 0, stream>>>(h, a1, a2, f1, f2);
    aggregate<<<N_NODES, 256, 0, stream>>>(mask, h, f1, f2, fc_w, fc_b, out);
}

// Round 2
// 160.367 us; speedup vs baseline: 1.0486x; 1.0486x over previous
//
#include <hip/hip_runtime.h>
#include <hip/hip_bf16.h>
#include <stdint.h>
#include <math.h>

#define N_NODES 8192
#define NDIM    512
#define HID     256
#define NCLS    16
#define NE      262144
#define MWR     256   // mask words per row (8192/32)
#define CAP     256   // max stored neighbors/row (Poisson lambda~33 -> P(>128) ~ 0)

static __device__ __forceinline__ ushort f2bf(float f) {
    uint32_t u = __float_as_uint(f);
    uint32_t r = (u + 0x7FFFu + ((u >> 16) & 1u)) >> 16;   // round-to-nearest-even
    return (ushort)r;
}
static __device__ __forceinline__ float bf2f(ushort u) {
    return __uint_as_float(((uint32_t)u) << 16);
}

// ---------------------------------------------------------------------------
// Dense adjacency bitmask (dedupes duplicates) + self loops. Dtype of the edge
// buffer (int32 vs int64) detected inline: read first 32 slots as int64; any
// value outside [0,N) => the data is int32 pairs.
__global__ __launch_bounds__(256) void build_mask(const void* __restrict__ edges,
                                                  uint32_t* __restrict__ mask) {
    const long long* p64 = (const long long*)edges;
    long long probe = p64[threadIdx.x & 31];
    const int is32 = __any(probe < 0 || probe >= (long long)N_NODES);

    int idx = blockIdx.x * blockDim.x + threadIdx.x;
    if (idx < NE) {
        int src, dst;
        if (is32) {
            const int* p = (const int*)edges;
            src = p[idx]; dst = p[NE + idx];
        } else {
            src = (int)p64[idx]; dst = (int)p64[NE + idx];
        }
        atomicOr(&mask[src * MWR + (dst >> 5)], 1u << (dst & 31));
    } else {
        int d = idx - NE;
        if (d < N_NODES) atomicOr(&mask[d * MWR + (d >> 5)], 1u << (d & 31));
    }
}

// ---------------------------------------------------------------------------
// h = x @ W^T (8192x512x256 f32). Output stored as bf16 (gather operand).
// Epilogue also computes f1 = h@a1, f2 = h@a2 from the exact f32 accumulators
// (16-lane shfl reduce + atomicAdd of per-block partials).
__global__ __launch_bounds__(256) void gemm_h(const float* __restrict__ x,
                                              const float* __restrict__ W,
                                              const float* __restrict__ a1,
                                              const float* __restrict__ a2,
                                              ushort* __restrict__ hb,
                                              float* __restrict__ f1,
                                              float* __restrict__ f2) {
    __shared__ float xs[32][68];
    __shared__ float ws[32][68];
    const int tid  = threadIdx.x;
    const int row0 = blockIdx.y * 64;
    const int col0 = blockIdx.x * 64;
    const int lr = tid >> 3;          // 0..31
    const int lc = (tid & 7) << 2;    // 0,4,...,28
    const int tx = tid & 15;
    const int ty = tid >> 4;
    float acc[4][4] = {};
    const float* xp = x + (size_t)(row0 + lr) * NDIM + lc;
    const float* wp = W + (size_t)(col0 + lr) * NDIM + lc;

    for (int k0 = 0; k0 < NDIM; k0 += 32) {
        float4 xa = *(const float4*)(xp + k0);
        float4 xb = *(const float4*)(xp + k0 + 32 * NDIM);
        float4 wa = *(const float4*)(wp + k0);
        float4 wb = *(const float4*)(wp + k0 + 32 * NDIM);
        __syncthreads();
        xs[lc + 0][lr] = xa.x; xs[lc + 1][lr] = xa.y; xs[lc + 2][lr] = xa.z; xs[lc + 3][lr] = xa.w;
        xs[lc + 0][lr + 32] = xb.x; xs[lc + 1][lr + 32] = xb.y; xs[lc + 2][lr + 32] = xb.z; xs[lc + 3][lr + 32] = xb.w;
        ws[lc + 0][lr] = wa.x; ws[lc + 1][lr] = wa.y; ws[lc + 2][lr] = wa.z; ws[lc + 3][lr] = wa.w;
        ws[lc + 0][lr + 32] = wb.x; ws[lc + 1][lr + 32] = wb.y; ws[lc + 2][lr + 32] = wb.z; ws[lc + 3][lr + 32] = wb.w;
        __syncthreads();
        #pragma unroll
        for (int kk = 0; kk < 32; ++kk) {
            float4 a = *(const float4*)&xs[kk][ty << 2];
            float4 b = *(const float4*)&ws[kk][tx << 2];
            acc[0][0] += a.x * b.x; acc[0][1] += a.x * b.y; acc[0][2] += a.x * b.z; acc[0][3] += a.x * b.w;
            acc[1][0] += a.y * b.x; acc[1][1] += a.y * b.y; acc[1][2] += a.y * b.z; acc[1][3] += a.y * b.w;
            acc[2][0] += a.z * b.x; acc[2][1] += a.z * b.y; acc[2][2] += a.z * b.z; acc[2][3] += a.z * b.w;
            acc[3][0] += a.w * b.x; acc[3][1] += a.w * b.y; acc[3][2] += a.w * b.z; acc[3][3] += a.w * b.w;
        }
    }
    // Epilogue: bf16 store of h + f1/f2 partial dot products.
    const float4 a1c = *(const float4*)&a1[col0 + (tx << 2)];
    const float4 a2c = *(const float4*)&a2[col0 + (tx << 2)];
    #pragma unroll
    for (int i = 0; i < 4; ++i) {
        const int r = row0 + (ty << 2) + i;
        ushort4 hv;
        hv.x = f2bf(acc[i][0]); hv.y = f2bf(acc[i][1]);
        hv.z = f2bf(acc[i][2]); hv.w = f2bf(acc[i][3]);
        *(ushort4*)&hb[(size_t)r * HID + col0 + (tx << 2)] = hv;
        float p1 = acc[i][0] * a1c.x + acc[i][1] * a1c.y + acc[i][2] * a1c.z + acc[i][3] * a1c.w;
        float p2 = acc[i][0] * a2c.x + acc[i][1] * a2c.y + acc[i][2] * a2c.z + acc[i][3] * a2c.w;
        #pragma unroll
        for (int msk = 8; msk; msk >>= 1) {
            p1 += __shfl_xor(p1, msk);
            p2 += __shfl_xor(p2, msk);
        }
        if (tx == 0) {
            atomicAdd(&f1[r], p1);
            atomicAdd(&f2[r], p2);
        }
    }
}

// ---------------------------------------------------------------------------
// Per-row masked softmax + out = elu(alpha@h) + FC. One 256-thread block/row.
__global__ __launch_bounds__(256) void aggregate(const uint32_t* __restrict__ mask,
                                                 const ushort* __restrict__ hb,
                                                 const float* __restrict__ f1,
                                                 const float* __restrict__ f2,
                                                 const float* __restrict__ fc_w,
                                                 const float* __restrict__ fc_b,
                                                 float* __restrict__ out) {
    __shared__ int   sh_j[CAP];
    __shared__ float sh_v[CAP];
    __shared__ int   sh_cnt;
    __shared__ float red_m[4];
    __shared__ float red_s[4];
    __shared__ float sh_out[HID];
    __shared__ float sh_fc[256];

    const int row  = blockIdx.x;
    const int tid  = threadIdx.x;
    const int lane = tid & 63;
    const int wv   = tid >> 6;
    if (tid == 0) sh_cnt = 0;
    __syncthreads();

    const float fi = f1[row];
    uint32_t w = mask[(size_t)row * MWR + tid];
    float m = -INFINITY, s = 0.f;
    while (w) {
        int b = __ffs(w) - 1;
        w &= w - 1;
        int j = (tid << 5) + b;
        float z = fi + f2[j];
        float v = z > 0.f ? z : 0.01f * z;       // leaky_relu(0.01)
        if (v != 0.f) {                           // exact zeros masked (ref quirk)
            int slot = atomicAdd(&sh_cnt, 1);
            if (slot < CAP) { sh_j[slot] = j; sh_v[slot] = v; }
            if (v > m) { s = s * __expf(m - v) + 1.f; m = v; }
            else       { s += __expf(v - m); }
        }
    }
    // Wave reduce: max first, then rescaled sum.
    float M = m;
    #pragma unroll
    for (int off = 32; off; off >>= 1) M = fmaxf(M, __shfl_xor(M, off));
    float S = (m == -INFINITY) ? 0.f : s * __expf(m - M);
    #pragma unroll
    for (int off = 32; off; off >>= 1) S += __shfl_xor(S, off);
    if (lane == 0) { red_m[wv] = M; red_s[wv] = S; }
    __syncthreads();
    // Cross-wave combine (redundant per thread; 4 entries).
    float Mt = fmaxf(fmaxf(red_m[0], red_m[1]), fmaxf(red_m[2], red_m[3]));
    float St = 0.f;
    #pragma unroll
    for (int k = 0; k < 4; ++k)
        if (red_m[k] != -INFINITY) St += red_s[k] * __expf(red_m[k] - Mt);

    const int cnt = min(sh_cnt, CAP);
    const float inv = 1.f / St;
    for (int n = tid; n < cnt; n += 256) sh_v[n] = __expf(sh_v[n] - Mt) * inv;
    __syncthreads();

    // alpha @ h : thread t owns hidden column t; unroll 4 neighbors for MLP.
    float acc = 0.f;
    const ushort* hcol = hb + tid;
    int n = 0;
    for (; n + 4 <= cnt; n += 4) {
        int j0 = sh_j[n+0], j1 = sh_j[n+1], j2 = sh_j[n+2], j3 = sh_j[n+3];
        float v0 = sh_v[n+0], v1 = sh_v[n+1], v2 = sh_v[n+2], v3 = sh_v[n+3];
        float h0 = bf2f(hcol[(size_t)j0 * HID]);
        float h1 = bf2f(hcol[(size_t)j1 * HID]);
        float h2 = bf2f(hcol[(size_t)j2 * HID]);
        float h3 = bf2f(hcol[(size_t)j3 * HID]);
        acc += v0 * h0 + v1 * h1 + v2 * h2 + v3 * h3;
    }
    for (; n < cnt; ++n) acc += sh_v[n] * bf2f(hcol[(size_t)sh_j[n] * HID]);

    sh_out[tid] = acc > 0.f ? acc : expm1f(acc);   // ELU
    __syncthreads();

    // FC: 16 classes x 16 column-segments.
    const int c   = tid >> 4;
    const int seg = tid & 15;
    float p = 0.f;
    #pragma unroll
    for (int u = 0; u < 16; ++u) {
        int t = seg * 16 + u;
        p += sh_out[t] * fc_w[c * HID + t];
    }
    sh_fc[tid] = p;
    __syncthreads();
    if (tid < NCLS) {
        float t = fc_b[tid];
        #pragma unroll
        for (int q = 0; q < 16; ++q) t += sh_fc[tid * 16 + q];
        out[(size_t)row * NCLS + tid] = t;
    }
}

// ---------------------------------------------------------------------------
extern "C" void kernel_launch(void* const* d_in, const int* in_sizes, int n_in,
                              void* d_out, int out_size, void* d_ws, size_t ws_size,
                              hipStream_t stream) {
    const float* x    = (const float*)d_in[0];
    const void*  ei   = d_in[1];
    const float* W    = (const float*)d_in[2];
    const float* a1   = (const float*)d_in[3];
    const float* a2   = (const float*)d_in[4];
    const float* fc_w = (const float*)d_in[5];
    const float* fc_b = (const float*)d_in[6];
    float* out = (float*)d_out;

    char* ws = (char*)d_ws;
    uint32_t* mask = (uint32_t*)ws;                               // 8 MB
    float*    f1   = (float*)(ws + 8388608);                      // 32 KB
    float*    f2   = (float*)(ws + 8388608 + 32768);              // 32 KB
    ushort*   hb   = (ushort*)(ws + 8388608 + 65536);             // 4 MB bf16 h

    // Zero mask + f1 + f2 in one pass.
    hipMemsetAsync(ws, 0, 8388608 + 65536, stream);
    const int total = NE + N_NODES;
    build_mask<<<(total + 255) / 256, 256, 0, stream>>>(ei, mask);
    gemm_h<<<dim3(HID / 64, N_NODES / 64), 256, 0, stream>>>(x, W, a1, a2, hb, f1, f2);
    aggregate<<<N_NODES, 256, 0, stream>>>(mask, hb, f1, f2, fc_w, fc_b, out);
}

// Round 3
// 151.908 us; speedup vs baseline: 1.1070x; 1.0557x over previous
//
#include <hip/hip_runtime.h>
#include <hip/hip_bf16.h>
#include <stdint.h>
#include <math.h>

#define N_NODES 8192
#define NDIM    512
#define HID     256
#define NCLS    16
#define NE      262144
#define MWR     256   // mask words per row (8192/32)
#define CAP     128   // max stored neighbors/row (Poisson lambda~33, P(>128)~0)

static __device__ __forceinline__ ushort f2bf(float f) {
    uint32_t u = __float_as_uint(f);
    uint32_t r = (u + 0x7FFFu + ((u >> 16) & 1u)) >> 16;   // round-to-nearest-even
    return (ushort)r;
}
static __device__ __forceinline__ float bf2f(ushort u) {
    return __uint_as_float(((uint32_t)u) << 16);
}
// Same-wave cross-lane LDS visibility: drain LDS ops + compiler fence.
static __device__ __forceinline__ void wave_lds_fence() {
    asm volatile("s_waitcnt lgkmcnt(0)" ::: "memory");
}

// ---------------------------------------------------------------------------
// Dense adjacency bitmask (dedupes duplicates) + self loops. Edge buffer dtype
// (int32 vs int64) detected inline from first 32 slots.
__global__ __launch_bounds__(256) void build_mask(const void* __restrict__ edges,
                                                  uint32_t* __restrict__ mask) {
    const long long* p64 = (const long long*)edges;
    long long probe = p64[threadIdx.x & 31];
    const int is32 = __any(probe < 0 || probe >= (long long)N_NODES);

    int idx = blockIdx.x * blockDim.x + threadIdx.x;
    if (idx < NE) {
        int src, dst;
        if (is32) {
            const int* p = (const int*)edges;
            src = p[idx]; dst = p[NE + idx];
        } else {
            src = (int)p64[idx]; dst = (int)p64[NE + idx];
        }
        atomicOr(&mask[src * MWR + (dst >> 5)], 1u << (dst & 31));
    } else {
        int d = idx - NE;
        if (d < N_NODES) atomicOr(&mask[d * MWR + (d >> 5)], 1u << (d & 31));
    }
}

// ---------------------------------------------------------------------------
// h = x @ W^T (8192x512x256 f32). bf16 h store; exact-f32 f1/f2 via epilogue
// atomics. (Unchanged from round 2 — known-good.)
__global__ __launch_bounds__(256) void gemm_h(const float* __restrict__ x,
                                              const float* __restrict__ W,
                                              const float* __restrict__ a1,
                                              const float* __restrict__ a2,
                                              ushort* __restrict__ hb,
                                              float* __restrict__ f1,
                                              float* __restrict__ f2) {
    __shared__ float xs[32][68];
    __shared__ float ws[32][68];
    const int tid  = threadIdx.x;
    const int row0 = blockIdx.y * 64;
    const int col0 = blockIdx.x * 64;
    const int lr = tid >> 3;
    const int lc = (tid & 7) << 2;
    const int tx = tid & 15;
    const int ty = tid >> 4;
    float acc[4][4] = {};
    const float* xp = x + (size_t)(row0 + lr) * NDIM + lc;
    const float* wp = W + (size_t)(col0 + lr) * NDIM + lc;

    for (int k0 = 0; k0 < NDIM; k0 += 32) {
        float4 xa = *(const float4*)(xp + k0);
        float4 xb = *(const float4*)(xp + k0 + 32 * NDIM);
        float4 wa = *(const float4*)(wp + k0);
        float4 wb = *(const float4*)(wp + k0 + 32 * NDIM);
        __syncthreads();
        xs[lc + 0][lr] = xa.x; xs[lc + 1][lr] = xa.y; xs[lc + 2][lr] = xa.z; xs[lc + 3][lr] = xa.w;
        xs[lc + 0][lr + 32] = xb.x; xs[lc + 1][lr + 32] = xb.y; xs[lc + 2][lr + 32] = xb.z; xs[lc + 3][lr + 32] = xb.w;
        ws[lc + 0][lr] = wa.x; ws[lc + 1][lr] = wa.y; ws[lc + 2][lr] = wa.z; ws[lc + 3][lr] = wa.w;
        ws[lc + 0][lr + 32] = wb.x; ws[lc + 1][lr + 32] = wb.y; ws[lc + 2][lr + 32] = wb.z; ws[lc + 3][lr + 32] = wb.w;
        __syncthreads();
        #pragma unroll
        for (int kk = 0; kk < 32; ++kk) {
            float4 a = *(const float4*)&xs[kk][ty << 2];
            float4 b = *(const float4*)&ws[kk][tx << 2];
            acc[0][0] += a.x * b.x; acc[0][1] += a.x * b.y; acc[0][2] += a.x * b.z; acc[0][3] += a.x * b.w;
            acc[1][0] += a.y * b.x; acc[1][1] += a.y * b.y; acc[1][2] += a.y * b.z; acc[1][3] += a.y * b.w;
            acc[2][0] += a.z * b.x; acc[2][1] += a.z * b.y; acc[2][2] += a.z * b.z; acc[2][3] += a.z * b.w;
            acc[3][0] += a.w * b.x; acc[3][1] += a.w * b.y; acc[3][2] += a.w * b.z; acc[3][3] += a.w * b.w;
        }
    }
    const float4 a1c = *(const float4*)&a1[col0 + (tx << 2)];
    const float4 a2c = *(const float4*)&a2[col0 + (tx << 2)];
    #pragma unroll
    for (int i = 0; i < 4; ++i) {
        const int r = row0 + (ty << 2) + i;
        ushort4 hv;
        hv.x = f2bf(acc[i][0]); hv.y = f2bf(acc[i][1]);
        hv.z = f2bf(acc[i][2]); hv.w = f2bf(acc[i][3]);
        *(ushort4*)&hb[(size_t)r * HID + col0 + (tx << 2)] = hv;
        float p1 = acc[i][0] * a1c.x + acc[i][1] * a1c.y + acc[i][2] * a1c.z + acc[i][3] * a1c.w;
        float p2 = acc[i][0] * a2c.x + acc[i][1] * a2c.y + acc[i][2] * a2c.z + acc[i][3] * a2c.w;
        #pragma unroll
        for (int msk = 8; msk; msk >>= 1) {
            p1 += __shfl_xor(p1, msk);
            p2 += __shfl_xor(p2, msk);
        }
        if (tx == 0) {
            atomicAdd(&f1[r], p1);
            atomicAdd(&f2[r], p2);
        }
    }
}

// ---------------------------------------------------------------------------
// ONE WAVE PER ROW. 4 waves/block, no __syncthreads anywhere.
// Per row: uint4 mask scan -> LDS list append (wave atomics) -> shfl softmax
// -> normalized weights -> coalesced ushort4 gather of h -> ELU -> FC.
__global__ __launch_bounds__(256) void aggregate(const uint32_t* __restrict__ mask,
                                                 const ushort* __restrict__ hb,
                                                 const float* __restrict__ f1,
                                                 const float* __restrict__ f2,
                                                 const float* __restrict__ fc_w,
                                                 const float* __restrict__ fc_b,
                                                 float* __restrict__ out) {
    __shared__ int   sh_j[4][CAP];
    __shared__ float sh_v[4][CAP];
    __shared__ float sh_o[4][HID];
    __shared__ int   sh_cnt[4];

    const int wv   = threadIdx.x >> 6;
    const int lane = threadIdx.x & 63;
    const int row  = blockIdx.x * 4 + wv;
    int*   jl = sh_j[wv];
    float* vl = sh_v[wv];
    float* ol = sh_o[wv];

    if (lane == 0) sh_cnt[wv] = 0;
    // lane0's ds_write precedes all lanes' ds_add in wave program order -> ordered.

    const float fi = f1[row];
    // 4 mask words per lane (coalesced 16B).
    uint4 mw = *(const uint4*)&mask[(size_t)row * MWR + lane * 4];

    float m = -INFINITY, s = 0.f;
    #pragma unroll
    for (int wi = 0; wi < 4; ++wi) {
        uint32_t w = (&mw.x)[wi];
        while (w) {
            int b = __ffs(w) - 1;
            w &= w - 1;
            int j = (lane * 4 + wi) * 32 + b;
            float z = fi + f2[j];
            float v = z > 0.f ? z : 0.01f * z;     // leaky_relu(0.01)
            if (v != 0.f) {                         // exact zeros masked (ref quirk)
                int slot = atomicAdd(&sh_cnt[wv], 1);
                if (slot < CAP) { jl[slot] = j; vl[slot] = v; }
                if (v > m) { s = s * __expf(m - v) + 1.f; m = v; }
                else       { s += __expf(v - m); }
            }
        }
    }
    // Wave softmax reduce: max, then rescaled sum.
    float M = m;
    #pragma unroll
    for (int off = 32; off; off >>= 1) M = fmaxf(M, __shfl_xor(M, off));
    float S = (m == -INFINITY) ? 0.f : s * __expf(m - M);
    #pragma unroll
    for (int off = 32; off; off >>= 1) S += __shfl_xor(S, off);

    const int cnt = min(sh_cnt[wv], CAP);
    wave_lds_fence();                               // appends visible wave-wide

    const float inv = 1.f / S;
    for (int n = lane; n < cnt; n += 64) vl[n] = __expf(vl[n] - M) * inv;
    wave_lds_fence();                               // normalized weights visible

    // alpha @ h : lane owns hidden cols 4*lane..4*lane+3 (ushort4 = 8B/lane).
    float a0 = 0.f, a1v = 0.f, a2v = 0.f, a3 = 0.f;
    const ushort* hcol = hb + lane * 4;
    int n = 0;
    for (; n + 4 <= cnt; n += 4) {
        #pragma unroll
        for (int u = 0; u < 4; ++u) {
            int j   = jl[n + u];
            float v = vl[n + u];
            ushort4 hv = *(const ushort4*)(hcol + (size_t)j * HID);
            a0 += v * bf2f(hv.x); a1v += v * bf2f(hv.y);
            a2v += v * bf2f(hv.z); a3 += v * bf2f(hv.w);
        }
    }
    for (; n < cnt; ++n) {
        int j   = jl[n];
        float v = vl[n];
        ushort4 hv = *(const ushort4*)(hcol + (size_t)j * HID);
        a0 += v * bf2f(hv.x); a1v += v * bf2f(hv.y);
        a2v += v * bf2f(hv.z); a3 += v * bf2f(hv.w);
    }
    // ELU, store out-row to LDS.
    float4 e;
    e.x = a0  > 0.f ? a0  : expm1f(a0);
    e.y = a1v > 0.f ? a1v : expm1f(a1v);
    e.z = a2v > 0.f ? a2v : expm1f(a2v);
    e.w = a3  > 0.f ? a3  : expm1f(a3);
    *(float4*)&ol[lane * 4] = e;
    wave_lds_fence();                               // out-row visible

    // FC: class c = lane>>2, quarter q = lane&3 covers cols q*64..q*64+63.
    const int c = lane >> 2;
    const int q = lane & 3;
    float p = 0.f;
    #pragma unroll
    for (int i = 0; i < 64; i += 4) {
        float4 o = *(const float4*)&ol[q * 64 + i];
        float4 w = *(const float4*)&fc_w[c * HID + q * 64 + i];
        p += o.x * w.x + o.y * w.y + o.z * w.z + o.w * w.w;
    }
    p += __shfl_xor(p, 1);
    p += __shfl_xor(p, 2);
    if (q == 0) out[(size_t)row * NCLS + c] = p + fc_b[c];
}

// ---------------------------------------------------------------------------
extern "C" void kernel_launch(void* const* d_in, const int* in_sizes, int n_in,
                              void* d_out, int out_size, void* d_ws, size_t ws_size,
                              hipStream_t stream) {
    const float* x    = (const float*)d_in[0];
    const void*  ei   = d_in[1];
    const float* W    = (const float*)d_in[2];
    const float* a1   = (const float*)d_in[3];
    const float* a2   = (const float*)d_in[4];
    const float* fc_w = (const float*)d_in[5];
    const float* fc_b = (const float*)d_in[6];
    float* out = (float*)d_out;

    char* ws = (char*)d_ws;
    uint32_t* mask = (uint32_t*)ws;                               // 8 MB
    float*    f1   = (float*)(ws + 8388608);                      // 32 KB
    float*    f2   = (float*)(ws + 8388608 + 32768);              // 32 KB
    ushort*   hb   = (ushort*)(ws + 8388608 + 65536);             // 4 MB bf16 h

    hipMemsetAsync(ws, 0, 8388608 + 65536, stream);               // mask + f1 + f2
    const int total = NE + N_NODES;
    build_mask<<<(total + 255) / 256, 256, 0, stream>>>(ei, mask);
    gemm_h<<<dim3(HID / 64, N_NODES / 64), 256, 0, stream>>>(x, W, a1, a2, hb, f1, f2);
    aggregate<<<N_NODES / 4, 256, 0, stream>>>(mask, hb, f1, f2, fc_w, fc_b, out);
}

// Round 9
// 133.534 us; speedup vs baseline: 1.2593x; 1.1376x over previous
//
#include <hip/hip_runtime.h>
#include <hip/hip_bf16.h>
#include <stdint.h>
#include <math.h>

#define N_NODES 8192
#define NDIM    512
#define HID     256
#define NCLS    16
#define NE      262144
#define MWR     256   // mask words per row (8192/32)
#define CAP     128   // max stored neighbors/row (Poisson lambda~33, P(>128)~0)

typedef __attribute__((ext_vector_type(8))) short short8;
typedef __attribute__((ext_vector_type(4))) float f32x4;

static __device__ __forceinline__ ushort f2bf(float f) {
    uint32_t u = __float_as_uint(f);
    uint32_t r = (u + 0x7FFFu + ((u >> 16) & 1u)) >> 16;   // round-to-nearest-even
    return (ushort)r;
}
static __device__ __forceinline__ float bf2f(ushort u) {
    return __uint_as_float(((uint32_t)u) << 16);
}
static __device__ __forceinline__ void wave_lds_fence() {
    asm volatile("s_waitcnt lgkmcnt(0)" ::: "memory");
}

// ---------------------------------------------------------------------------
// Dense adjacency bitmask (dedupes duplicates — duplicates matter for softmax
// weights) + self loops. Edge dtype (int32 vs int64) detected inline.
__global__ __launch_bounds__(256) void build_mask(const void* __restrict__ edges,
                                                  uint32_t* __restrict__ mask) {
    const long long* p64 = (const long long*)edges;
    long long probe = p64[threadIdx.x & 31];
    const int is32 = __any(probe < 0 || probe >= (long long)N_NODES);

    int idx = blockIdx.x * blockDim.x + threadIdx.x;
    if (idx < NE) {
        int src, dst;
        if (is32) {
            const int* p = (const int*)edges;
            src = p[idx]; dst = p[NE + idx];
        } else {
            src = (int)p64[idx]; dst = (int)p64[NE + idx];
        }
        atomicOr(&mask[src * MWR + (dst >> 5)], 1u << (dst & 31));
    } else {
        int d = idx - NE;
        if (d < N_NODES) atomicOr(&mask[d * MWR + (d >> 5)], 1u << (d & 31));
    }
}

// ---------------------------------------------------------------------------
// h = x @ W^T via bf16x3 MFMA (error-compensated: hi*hi + hi*lo + lo*hi).
// BM=BN=BK=64, 4 waves each 32x32 out (2x2 fragments of 16x16x32).
// LDS tiles XOR-swizzled (elem idx ^= (row&7)<<3) for conflict-free b128 reads.
// Epilogue: bf16 h store + exact-f32 f1/f2 partials (shfl reduce + atomicAdd).
__global__ __launch_bounds__(256) void gemm_h(const float* __restrict__ x,
                                              const float* __restrict__ W,
                                              const float* __restrict__ a1,
                                              const float* __restrict__ a2,
                                              ushort* __restrict__ hb,
                                              float* __restrict__ f1,
                                              float* __restrict__ f2) {
    __shared__ ushort lds[4][64 * 64];   // 0:A_hi 1:A_lo 2:B_hi 3:B_lo (32 KB)

    const int tid  = threadIdx.x;
    const int lane = tid & 63;
    const int wv   = tid >> 6;
    const int wr   = wv >> 1;           // wave row 0..1
    const int wc   = wv & 1;            // wave col 0..1
    const int cl   = lane & 15;         // frag col / row-low
    const int rg   = lane >> 4;         // frag reg-group 0..3

    // XCD-chunked bijective swizzle: 512 blocks, 64 per XCD contiguous logical.
    const int bid  = blockIdx.x;
    const int swz  = (bid & 7) * 64 + (bid >> 3);
    const int row0 = (swz >> 2) * 64;
    const int col0 = (swz & 3) * 64;

    const int tr  = tid >> 4;           // staging row 0..15
    const int tc4 = (tid & 15) << 2;    // staging k 0..60

    f32x4 acc[2][2] = {};

    for (int k0 = 0; k0 < NDIM; k0 += 64) {
        float4 av[4], bv[4];
        #pragma unroll
        for (int it = 0; it < 4; ++it) {
            av[it] = *(const float4*)&x[(size_t)(row0 + tr + it * 16) * NDIM + k0 + tc4];
            bv[it] = *(const float4*)&W[(size_t)(col0 + tr + it * 16) * NDIM + k0 + tc4];
        }
        __syncthreads();                 // prev-iter LDS reads done
        #pragma unroll
        for (int it = 0; it < 4; ++it) {
            const int r   = tr + it * 16;
            const int idx = (r * 64 + tc4) ^ ((r & 7) << 3);
            ushort4 hi, lo;
            hi.x = f2bf(av[it].x); lo.x = f2bf(av[it].x - bf2f(hi.x));
            hi.y = f2bf(av[it].y); lo.y = f2bf(av[it].y - bf2f(hi.y));
            hi.z = f2bf(av[it].z); lo.z = f2bf(av[it].z - bf2f(hi.z));
            hi.w = f2bf(av[it].w); lo.w = f2bf(av[it].w - bf2f(hi.w));
            *(ushort4*)&lds[0][idx] = hi;
            *(ushort4*)&lds[1][idx] = lo;
            hi.x = f2bf(bv[it].x); lo.x = f2bf(bv[it].x - bf2f(hi.x));
            hi.y = f2bf(bv[it].y); lo.y = f2bf(bv[it].y - bf2f(hi.y));
            hi.z = f2bf(bv[it].z); lo.z = f2bf(bv[it].z - bf2f(hi.z));
            hi.w = f2bf(bv[it].w); lo.w = f2bf(bv[it].w - bf2f(hi.w));
            *(ushort4*)&lds[2][idx] = hi;
            *(ushort4*)&lds[3][idx] = lo;
        }
        __syncthreads();

        #pragma unroll
        for (int ks = 0; ks < 2; ++ks) {
            short8 ah[2], al[2], bh[2], bl[2];
            const int ka = ks * 32 + rg * 8;
            #pragma unroll
            for (int i = 0; i < 2; ++i) {
                const int ra = wr * 32 + i * 16 + cl;
                const int ia = (ra * 64 + ka) ^ ((ra & 7) << 3);
                ah[i] = *(short8*)&lds[0][ia];
                al[i] = *(short8*)&lds[1][ia];
                const int rb = wc * 32 + i * 16 + cl;
                const int ib = (rb * 64 + ka) ^ ((rb & 7) << 3);
                bh[i] = *(short8*)&lds[2][ib];
                bl[i] = *(short8*)&lds[3][ib];
            }
            #pragma unroll
            for (int mi = 0; mi < 2; ++mi)
                #pragma unroll
                for (int ni = 0; ni < 2; ++ni) {
                    acc[mi][ni] = __builtin_amdgcn_mfma_f32_16x16x32_bf16(ah[mi], bh[ni], acc[mi][ni], 0, 0, 0);
                    acc[mi][ni] = __builtin_amdgcn_mfma_f32_16x16x32_bf16(ah[mi], bl[ni], acc[mi][ni], 0, 0, 0);
                    acc[mi][ni] = __builtin_amdgcn_mfma_f32_16x16x32_bf16(al[mi], bh[ni], acc[mi][ni], 0, 0, 0);
                }
        }
    }

    // Epilogue: C/D layout (16x16x32): col = lane&15, row = (lane>>4)*4 + reg.
    float a1c[2], a2c[2];
    #pragma unroll
    for (int ni = 0; ni < 2; ++ni) {
        const int c = col0 + wc * 32 + ni * 16 + cl;
        a1c[ni] = a1[c];
        a2c[ni] = a2[c];
    }
    #pragma unroll
    for (int mi = 0; mi < 2; ++mi) {
        #pragma unroll
        for (int reg = 0; reg < 4; ++reg) {
            const int r = row0 + wr * 32 + mi * 16 + rg * 4 + reg;
            float p1 = 0.f, p2 = 0.f;
            #pragma unroll
            for (int ni = 0; ni < 2; ++ni) {
                const float v = acc[mi][ni][reg];
                hb[(size_t)r * HID + col0 + wc * 32 + ni * 16 + cl] = f2bf(v);
                p1 += v * a1c[ni];
                p2 += v * a2c[ni];
            }
            p1 += __shfl_xor(p1, 1); p1 += __shfl_xor(p1, 2);
            p1 += __shfl_xor(p1, 4); p1 += __shfl_xor(p1, 8);
            p2 += __shfl_xor(p2, 1); p2 += __shfl_xor(p2, 2);
            p2 += __shfl_xor(p2, 4); p2 += __shfl_xor(p2, 8);
            if (cl == 0) {
                atomicAdd(&f1[r], p1);
                atomicAdd(&f2[r], p2);
            }
        }
    }
}

// ---------------------------------------------------------------------------
// ONE WAVE PER ROW (4 waves/block, no __syncthreads). Unchanged — known-good.
__global__ __launch_bounds__(256) void aggregate(const uint32_t* __restrict__ mask,
                                                 const ushort* __restrict__ hb,
                                                 const float* __restrict__ f1,
                                                 const float* __restrict__ f2,
                                                 const float* __restrict__ fc_w,
                                                 const float* __restrict__ fc_b,
                                                 float* __restrict__ out) {
    __shared__ int   sh_j[4][CAP];
    __shared__ float sh_v[4][CAP];
    __shared__ float sh_o[4][HID];
    __shared__ int   sh_cnt[4];

    const int wv   = threadIdx.x >> 6;
    const int lane = threadIdx.x & 63;
    const int row  = blockIdx.x * 4 + wv;
    int*   jl = sh_j[wv];
    float* vl = sh_v[wv];
    float* ol = sh_o[wv];

    if (lane == 0) sh_cnt[wv] = 0;

    const float fi = f1[row];
    uint4 mw = *(const uint4*)&mask[(size_t)row * MWR + lane * 4];

    float m = -INFINITY, s = 0.f;
    #pragma unroll
    for (int wi = 0; wi < 4; ++wi) {
        uint32_t w = (&mw.x)[wi];
        while (w) {
            int b = __ffs(w) - 1;
            w &= w - 1;
            int j = (lane * 4 + wi) * 32 + b;
            float z = fi + f2[j];
            float v = z > 0.f ? z : 0.01f * z;     // leaky_relu(0.01)
            if (v != 0.f) {                         // exact zeros masked (ref quirk)
                int slot = atomicAdd(&sh_cnt[wv], 1);
                if (slot < CAP) { jl[slot] = j; vl[slot] = v; }
                if (v > m) { s = s * __expf(m - v) + 1.f; m = v; }
                else       { s += __expf(v - m); }
            }
        }
    }
    float M = m;
    #pragma unroll
    for (int off = 32; off; off >>= 1) M = fmaxf(M, __shfl_xor(M, off));
    float S = (m == -INFINITY) ? 0.f : s * __expf(m - M);
    #pragma unroll
    for (int off = 32; off; off >>= 1) S += __shfl_xor(S, off);

    const int cnt = min(sh_cnt[wv], CAP);
    wave_lds_fence();

    const float inv = 1.f / S;
    for (int n = lane; n < cnt; n += 64) vl[n] = __expf(vl[n] - M) * inv;
    wave_lds_fence();

    float a0 = 0.f, a1v = 0.f, a2v = 0.f, a3 = 0.f;
    const ushort* hcol = hb + lane * 4;
    int n = 0;
    for (; n + 4 <= cnt; n += 4) {
        #pragma unroll
        for (int u = 0; u < 4; ++u) {
            int j   = jl[n + u];
            float v = vl[n + u];
            ushort4 hv = *(const ushort4*)(hcol + (size_t)j * HID);
            a0 += v * bf2f(hv.x); a1v += v * bf2f(hv.y);
            a2v += v * bf2f(hv.z); a3 += v * bf2f(hv.w);
        }
    }
    for (; n < cnt; ++n) {
        int j   = jl[n];
        float v = vl[n];
        ushort4 hv = *(const ushort4*)(hcol + (size_t)j * HID);
        a0 += v * bf2f(hv.x); a1v += v * bf2f(hv.y);
        a2v += v * bf2f(hv.z); a3 += v * bf2f(hv.w);
    }
    float4 e;
    e.x = a0  > 0.f ? a0  : expm1f(a0);
    e.y = a1v > 0.f ? a1v : expm1f(a1v);
    e.z = a2v > 0.f ? a2v : expm1f(a2v);
    e.w = a3  > 0.f ? a3  : expm1f(a3);
    *(float4*)&ol[lane * 4] = e;
    wave_lds_fence();

    const int c = lane >> 2;
    const int q = lane & 3;
    float p = 0.f;
    #pragma unroll
    for (int i = 0; i < 64; i += 4) {
        float4 o = *(const float4*)&ol[q * 64 + i];
        float4 w = *(const float4*)&fc_w[c * HID + q * 64 + i];
        p += o.x * w.x + o.y * w.y + o.z * w.z + o.w * w.w;
    }
    p += __shfl_xor(p, 1);
    p += __shfl_xor(p, 2);
    if (q == 0) out[(size_t)row * NCLS + c] = p + fc_b[c];
}

// ---------------------------------------------------------------------------
extern "C" void kernel_launch(void* const* d_in, const int* in_sizes, int n_in,
                              void* d_out, int out_size, void* d_ws, size_t ws_size,
                              hipStream_t stream) {
    const float* x    = (const float*)d_in[0];
    const void*  ei   = d_in[1];
    const float* W    = (const float*)d_in[2];
    const float* a1   = (const float*)d_in[3];
    const float* a2   = (const float*)d_in[4];
    const float* fc_w = (const float*)d_in[5];
    const float* fc_b = (const float*)d_in[6];
    float* out = (float*)d_out;

    char* ws = (char*)d_ws;
    uint32_t* mask = (uint32_t*)ws;                               // 8 MB
    float*    f1   = (float*)(ws + 8388608);                      // 32 KB
    float*    f2   = (float*)(ws + 8388608 + 32768);              // 32 KB
    ushort*   hb   = (ushort*)(ws + 8388608 + 65536);             // 4 MB bf16 h

    hipMemsetAsync(ws, 0, 8388608 + 65536, stream);               // mask + f1 + f2
    const int total = NE + N_NODES;
    build_mask<<<(total + 255) / 256, 256, 0, stream>>>(ei, mask);
    gemm_h<<<512, 256, 0, stream>>>(x, W, a1, a2, hb, f1, f2);
    aggregate<<<N_NODES / 4, 256, 0, stream>>>(mask, hb, f1, f2, fc_w, fc_b, out);
}

// Round 10
// 133.146 us; speedup vs baseline: 1.2629x; 1.0029x over previous
//
#include <hip/hip_runtime.h>
#include <hip/hip_bf16.h>
#include <stdint.h>
#include <math.h>

#define N_NODES 8192
#define NDIM    512
#define HID     256
#define NCLS    16
#define NE      262144
#define MWR     256   // mask words per row (8192/32)
#define CAP     128   // max stored neighbors/row (Poisson lambda~33, P(>128)~0)

typedef __attribute__((ext_vector_type(8))) short short8;
typedef __attribute__((ext_vector_type(4))) float f32x4;

static __device__ __forceinline__ ushort f2bf(float f) {
    uint32_t u = __float_as_uint(f);
    uint32_t r = (u + 0x7FFFu + ((u >> 16) & 1u)) >> 16;   // round-to-nearest-even
    return (ushort)r;
}
static __device__ __forceinline__ float bf2f(ushort u) {
    return __uint_as_float(((uint32_t)u) << 16);
}
static __device__ __forceinline__ void wave_lds_fence() {
    asm volatile("s_waitcnt lgkmcnt(0)" ::: "memory");
}

// ---------------------------------------------------------------------------
// Dense adjacency bitmask (dedupes duplicates — duplicates matter for softmax
// weights) + self loops. Edge dtype (int32 vs int64) detected inline.
__global__ __launch_bounds__(256) void build_mask(const void* __restrict__ edges,
                                                  uint32_t* __restrict__ mask) {
    const long long* p64 = (const long long*)edges;
    long long probe = p64[threadIdx.x & 31];
    const int is32 = __any(probe < 0 || probe >= (long long)N_NODES);

    int idx = blockIdx.x * blockDim.x + threadIdx.x;
    if (idx < NE) {
        int src, dst;
        if (is32) {
            const int* p = (const int*)edges;
            src = p[idx]; dst = p[NE + idx];
        } else {
            src = (int)p64[idx]; dst = (int)p64[NE + idx];
        }
        atomicOr(&mask[src * MWR + (dst >> 5)], 1u << (dst & 31));
    } else {
        int d = idx - NE;
        if (d < N_NODES) atomicOr(&mask[d * MWR + (d >> 5)], 1u << (d & 31));
    }
}

// ---------------------------------------------------------------------------
// h = x @ W^T via bf16x3 MFMA (error-compensated: hi*hi + hi*lo + lo*hi).
// UNCHANGED from round 9 (known-good, off the top-5).
__global__ __launch_bounds__(256) void gemm_h(const float* __restrict__ x,
                                              const float* __restrict__ W,
                                              const float* __restrict__ a1,
                                              const float* __restrict__ a2,
                                              ushort* __restrict__ hb,
                                              float* __restrict__ f1,
                                              float* __restrict__ f2) {
    __shared__ ushort lds[4][64 * 64];   // 0:A_hi 1:A_lo 2:B_hi 3:B_lo (32 KB)

    const int tid  = threadIdx.x;
    const int lane = tid & 63;
    const int wv   = tid >> 6;
    const int wr   = wv >> 1;           // wave row 0..1
    const int wc   = wv & 1;            // wave col 0..1
    const int cl   = lane & 15;         // frag col / row-low
    const int rg   = lane >> 4;         // frag reg-group 0..3

    const int bid  = blockIdx.x;
    const int swz  = (bid & 7) * 64 + (bid >> 3);
    const int row0 = (swz >> 2) * 64;
    const int col0 = (swz & 3) * 64;

    const int tr  = tid >> 4;           // staging row 0..15
    const int tc4 = (tid & 15) << 2;    // staging k 0..60

    f32x4 acc[2][2] = {};

    for (int k0 = 0; k0 < NDIM; k0 += 64) {
        float4 av[4], bv[4];
        #pragma unroll
        for (int it = 0; it < 4; ++it) {
            av[it] = *(const float4*)&x[(size_t)(row0 + tr + it * 16) * NDIM + k0 + tc4];
            bv[it] = *(const float4*)&W[(size_t)(col0 + tr + it * 16) * NDIM + k0 + tc4];
        }
        __syncthreads();
        #pragma unroll
        for (int it = 0; it < 4; ++it) {
            const int r   = tr + it * 16;
            const int idx = (r * 64 + tc4) ^ ((r & 7) << 3);
            ushort4 hi, lo;
            hi.x = f2bf(av[it].x); lo.x = f2bf(av[it].x - bf2f(hi.x));
            hi.y = f2bf(av[it].y); lo.y = f2bf(av[it].y - bf2f(hi.y));
            hi.z = f2bf(av[it].z); lo.z = f2bf(av[it].z - bf2f(hi.z));
            hi.w = f2bf(av[it].w); lo.w = f2bf(av[it].w - bf2f(hi.w));
            *(ushort4*)&lds[0][idx] = hi;
            *(ushort4*)&lds[1][idx] = lo;
            hi.x = f2bf(bv[it].x); lo.x = f2bf(bv[it].x - bf2f(hi.x));
            hi.y = f2bf(bv[it].y); lo.y = f2bf(bv[it].y - bf2f(hi.y));
            hi.z = f2bf(bv[it].z); lo.z = f2bf(bv[it].z - bf2f(hi.z));
            hi.w = f2bf(bv[it].w); lo.w = f2bf(bv[it].w - bf2f(hi.w));
            *(ushort4*)&lds[2][idx] = hi;
            *(ushort4*)&lds[3][idx] = lo;
        }
        __syncthreads();

        #pragma unroll
        for (int ks = 0; ks < 2; ++ks) {
            short8 ah[2], al[2], bh[2], bl[2];
            const int ka = ks * 32 + rg * 8;
            #pragma unroll
            for (int i = 0; i < 2; ++i) {
                const int ra = wr * 32 + i * 16 + cl;
                const int ia = (ra * 64 + ka) ^ ((ra & 7) << 3);
                ah[i] = *(short8*)&lds[0][ia];
                al[i] = *(short8*)&lds[1][ia];
                const int rb = wc * 32 + i * 16 + cl;
                const int ib = (rb * 64 + ka) ^ ((rb & 7) << 3);
                bh[i] = *(short8*)&lds[2][ib];
                bl[i] = *(short8*)&lds[3][ib];
            }
            #pragma unroll
            for (int mi = 0; mi < 2; ++mi)
                #pragma unroll
                for (int ni = 0; ni < 2; ++ni) {
                    acc[mi][ni] = __builtin_amdgcn_mfma_f32_16x16x32_bf16(ah[mi], bh[ni], acc[mi][ni], 0, 0, 0);
                    acc[mi][ni] = __builtin_amdgcn_mfma_f32_16x16x32_bf16(ah[mi], bl[ni], acc[mi][ni], 0, 0, 0);
                    acc[mi][ni] = __builtin_amdgcn_mfma_f32_16x16x32_bf16(al[mi], bh[ni], acc[mi][ni], 0, 0, 0);
                }
        }
    }

    float a1c[2], a2c[2];
    #pragma unroll
    for (int ni = 0; ni < 2; ++ni) {
        const int c = col0 + wc * 32 + ni * 16 + cl;
        a1c[ni] = a1[c];
        a2c[ni] = a2[c];
    }
    #pragma unroll
    for (int mi = 0; mi < 2; ++mi) {
        #pragma unroll
        for (int reg = 0; reg < 4; ++reg) {
            const int r = row0 + wr * 32 + mi * 16 + rg * 4 + reg;
            float p1 = 0.f, p2 = 0.f;
            #pragma unroll
            for (int ni = 0; ni < 2; ++ni) {
                const float v = acc[mi][ni][reg];
                hb[(size_t)r * HID + col0 + wc * 32 + ni * 16 + cl] = f2bf(v);
                p1 += v * a1c[ni];
                p2 += v * a2c[ni];
            }
            p1 += __shfl_xor(p1, 1); p1 += __shfl_xor(p1, 2);
            p1 += __shfl_xor(p1, 4); p1 += __shfl_xor(p1, 8);
            p2 += __shfl_xor(p2, 1); p2 += __shfl_xor(p2, 2);
            p2 += __shfl_xor(p2, 4); p2 += __shfl_xor(p2, 8);
            if (cl == 0) {
                atomicAdd(&f1[r], p1);
                atomicAdd(&f2[r], p2);
            }
        }
    }
}

// ---------------------------------------------------------------------------
// ONE WAVE PER ROW. NEW: atomic-free list build via shfl_up prefix-sum
// (pass A: count+online-softmax; pass B: compacted writes), gather unroll x8.
__global__ __launch_bounds__(256) void aggregate(const uint32_t* __restrict__ mask,
                                                 const ushort* __restrict__ hb,
                                                 const float* __restrict__ f1,
                                                 const float* __restrict__ f2,
                                                 const float* __restrict__ fc_w,
                                                 const float* __restrict__ fc_b,
                                                 float* __restrict__ out) {
    __shared__ int   sh_j[4][CAP];
    __shared__ float sh_v[4][CAP];
    __shared__ float sh_o[4][HID];

    const int wv   = threadIdx.x >> 6;
    const int lane = threadIdx.x & 63;
    const int row  = blockIdx.x * 4 + wv;
    int*   jl = sh_j[wv];
    float* vl = sh_v[wv];
    float* ol = sh_o[wv];

    const float fi = f1[row];
    uint4 mw = *(const uint4*)&mask[(size_t)row * MWR + lane * 4];

    // Pass A: per-lane count of valid edges + online (max,sum). No LDS traffic.
    float m = -INFINITY, s = 0.f;
    int c = 0;
    #pragma unroll
    for (int wi = 0; wi < 4; ++wi) {
        uint32_t w = (&mw.x)[wi];
        while (w) {
            int b = __ffs(w) - 1;
            w &= w - 1;
            int j = (lane * 4 + wi) * 32 + b;
            float z = fi + f2[j];
            float v = z > 0.f ? z : 0.01f * z;     // leaky_relu(0.01)
            if (v != 0.f) {                         // exact zeros masked (ref quirk)
                ++c;
                if (v > m) { s = s * __expf(m - v) + 1.f; m = v; }
                else       { s += __expf(v - m); }
            }
        }
    }
    // Exclusive prefix-sum of c across the wave (6 shfl_up steps).
    int pre = c;
    #pragma unroll
    for (int off = 1; off < 64; off <<= 1) {
        int t = __shfl_up(pre, off);
        if (lane >= off) pre += t;
    }
    const int base = pre - c;
    int cnt = __shfl(pre, 63);

    // Wave softmax reduce: max, then rescaled sum.
    float M = m;
    #pragma unroll
    for (int off = 32; off; off >>= 1) M = fmaxf(M, __shfl_xor(M, off));
    float S = (m == -INFINITY) ? 0.f : s * __expf(m - M);
    #pragma unroll
    for (int off = 32; off; off >>= 1) S += __shfl_xor(S, off);

    // Pass B: re-scan, write compacted (j, v) at [base..base+c) — no atomics.
    int k = base;
    #pragma unroll
    for (int wi = 0; wi < 4; ++wi) {
        uint32_t w = (&mw.x)[wi];
        while (w) {
            int b = __ffs(w) - 1;
            w &= w - 1;
            int j = (lane * 4 + wi) * 32 + b;
            float z = fi + f2[j];
            float v = z > 0.f ? z : 0.01f * z;
            if (v != 0.f) {
                if (k < CAP) { jl[k] = j; vl[k] = v; }
                ++k;
            }
        }
    }
    cnt = min(cnt, CAP);
    wave_lds_fence();                               // list visible wave-wide

    const float inv = 1.f / S;
    for (int n = lane; n < cnt; n += 64) vl[n] = __expf(vl[n] - M) * inv;
    wave_lds_fence();                               // normalized weights visible

    // alpha @ h : lane owns hidden cols 4*lane..4*lane+3 (ushort4 = 8B/lane).
    float a0 = 0.f, a1v = 0.f, a2v = 0.f, a3 = 0.f;
    const ushort* hcol = hb + lane * 4;
    int n = 0;
    for (; n + 8 <= cnt; n += 8) {
        #pragma unroll
        for (int u = 0; u < 8; ++u) {
            int j   = jl[n + u];
            float v = vl[n + u];
            ushort4 hv = *(const ushort4*)(hcol + (size_t)j * HID);
            a0 += v * bf2f(hv.x); a1v += v * bf2f(hv.y);
            a2v += v * bf2f(hv.z); a3 += v * bf2f(hv.w);
        }
    }
    for (; n < cnt; ++n) {
        int j   = jl[n];
        float v = vl[n];
        ushort4 hv = *(const ushort4*)(hcol + (size_t)j * HID);
        a0 += v * bf2f(hv.x); a1v += v * bf2f(hv.y);
        a2v += v * bf2f(hv.z); a3 += v * bf2f(hv.w);
    }
    float4 e;
    e.x = a0  > 0.f ? a0  : expm1f(a0);
    e.y = a1v > 0.f ? a1v : expm1f(a1v);
    e.z = a2v > 0.f ? a2v : expm1f(a2v);
    e.w = a3  > 0.f ? a3  : expm1f(a3);
    *(float4*)&ol[lane * 4] = e;
    wave_lds_fence();                               // out-row visible

    // FC: class c = lane>>2, quarter q = lane&3 covers cols q*64..q*64+63.
    const int cc = lane >> 2;
    const int q  = lane & 3;
    float p = 0.f;
    #pragma unroll
    for (int i = 0; i < 64; i += 4) {
        float4 o = *(const float4*)&ol[q * 64 + i];
        float4 w = *(const float4*)&fc_w[cc * HID + q * 64 + i];
        p += o.x * w.x + o.y * w.y + o.z * w.z + o.w * w.w;
    }
    p += __shfl_xor(p, 1);
    p += __shfl_xor(p, 2);
    if (q == 0) out[(size_t)row * NCLS + cc] = p + fc_b[cc];
}

// ---------------------------------------------------------------------------
extern "C" void kernel_launch(void* const* d_in, const int* in_sizes, int n_in,
                              void* d_out, int out_size, void* d_ws, size_t ws_size,
                              hipStream_t stream) {
    const float* x    = (const float*)d_in[0];
    const void*  ei   = d_in[1];
    const float* W    = (const float*)d_in[2];
    const float* a1   = (const float*)d_in[3];
    const float* a2   = (const float*)d_in[4];
    const float* fc_w = (const float*)d_in[5];
    const float* fc_b = (const float*)d_in[6];
    float* out = (float*)d_out;

    char* ws = (char*)d_ws;
    uint32_t* mask = (uint32_t*)ws;                               // 8 MB
    float*    f1   = (float*)(ws + 8388608);                      // 32 KB
    float*    f2   = (float*)(ws + 8388608 + 32768);              // 32 KB
    ushort*   hb   = (ushort*)(ws + 8388608 + 65536);             // 4 MB bf16 h

    hipMemsetAsync(ws, 0, 8388608 + 65536, stream);               // mask + f1 + f2
    const int total = NE + N_NODES;
    build_mask<<<(total + 255) / 256, 256, 0, stream>>>(ei, mask);
    gemm_h<<<512, 256, 0, stream>>>(x, W, a1, a2, hb, f1, f2);
    aggregate<<<N_NODES / 4, 256, 0, stream>>>(mask, hb, f1, f2, fc_w, fc_b, out);
}